// Round 1
// baseline (473.015 us; speedup 1.0000x reference)
//
#include <hip/hip_runtime.h>
#include <hip/hip_cooperative_groups.h>

namespace cg = cooperative_groups;

#define Bn 16
#define Ln 8400
#define Cn 1
#define Ngt 32
#define Kpt 68
#define TOPKN 13
#define EPSF 1e-9f
#define CAP 2048   // candidate capacity per (b,i); expected max ~350 for this data

typedef unsigned int u32;

// Output element offsets (float32 elements, flat concat in return order)
#define OFF_LABELS   0
#define OFF_BBOXES   134400
#define OFF_SCORES   672000
#define OFF_POSES    806400
#define OFF_VERTS    28224000
#define OFF_ROT      55641600
#define OFF_GTIDX    56851200

#define NBLK 512     // == Bn*Ngt, one block per (b,i) in phase 1; 2 blocks/CU co-resident
#define NTHR 256
#define GSZ  (NBLK * NTHR)

__device__ __forceinline__ float iou_box(float gx0, float gy0, float gx1, float gy1,
                                         float4 p) {
    float ix0 = fmaxf(gx0, p.x), iy0 = fmaxf(gy0, p.y);
    float ix1 = fminf(gx1, p.z), iy1 = fminf(gy1, p.w);
    float ov = fmaxf(ix1 - ix0, 0.f) * fmaxf(iy1 - iy0, 0.f);
    float a1 = fmaxf(gx1 - gx0, 0.f) * fmaxf(gy1 - gy0, 0.f);
    float a2 = fmaxf(p.z - p.x, 0.f) * fmaxf(p.w - p.y, 0.f);
    return ov / (a1 + a2 - ov + EPSF);
}

// Single fused cooperative kernel.
// phase 0: zero posmask/maxm/maxiou (replaces hipMemsetAsync dispatch)
// phase 1: per-(b,i) inside-candidate compaction + exact top-13 (k1)
// phase 2: per-(b,l) multi-assignment resolve + per-instance maxes (k2)
// phase 3: big gathers + epilogue (k3)
__global__ void __launch_bounds__(256, 2) fused(
    const float* __restrict__ pred_scores, const float* __restrict__ pred_bboxes,
    const float* __restrict__ anchors, const int* __restrict__ gt_labels,
    const float* __restrict__ gt_bboxes, const float* __restrict__ gt_poses,
    const float* __restrict__ gt_verts, const float* __restrict__ gt_rot,
    const float* __restrict__ pad_mask, const int* __restrict__ bg_index_p,
    u32* __restrict__ posmask, float* __restrict__ maxm, float* __restrict__ maxiou,
    u32* __restrict__ finalmask, int* __restrict__ srcidx, float* __restrict__ met_sel,
    float* __restrict__ out)
{
    cg::grid_group gg = cg::this_grid();
    const int tid = threadIdx.x;
    const int gtid = blockIdx.x * NTHR + tid;

    // ---------------- phase 0: zero workspace accumulators ----------------
    {
        // posmask (Bn*Ln u32), maxm (Bn*Ngt f32), maxiou (Bn*Ngt f32) are contiguous
        const int nz = Bn * Ln + 2 * Bn * Ngt;
        for (int w = gtid; w < nz; w += GSZ) posmask[w] = 0u;
    }
    gg.sync();

    // ---------------- phase 1: candidate compaction + top-13 ----------------
    {
        __shared__ float cmet[CAP];
        __shared__ int   cidx[CAP];
        __shared__ int   count;
        __shared__ float rv[4];
        __shared__ int   rl[4], rc[4];
        __shared__ int   sel[TOPKN];

        const int bi = blockIdx.x;          // b*Ngt + i, grid is exactly Bn*Ngt
        const int b = bi >> 5, i = bi & 31;

        if (pad_mask[bi] != 0.f) {          // uniform per block
            const float gx0 = gt_bboxes[bi*4+0];
            const float gy0 = gt_bboxes[bi*4+1];
            const float gx1 = gt_bboxes[bi*4+2];
            const float gy1 = gt_bboxes[bi*4+3];
            const int   label = gt_labels[bi];

            const float4* pb = (const float4*)(pred_bboxes + (size_t)b * Ln * 4);
            const float*  ps = pred_scores + (size_t)b * Ln * Cn;
            const float2* ap = (const float2*)anchors;

            if (tid == 0) count = 0;
            __syncthreads();

            for (int l = tid; l < Ln; l += NTHR) {
                float2 av = ap[l];
                float dmin = fminf(fminf(av.x - gx0, av.y - gy0),
                                   fminf(gx1 - av.x, gy1 - av.y));
                if (dmin > EPSF) {
                    float4 pv = pb[l];
                    float iou = iou_box(gx0, gy0, gx1, gy1, pv);
                    float sc = ps[l * Cn + label];
                    float i2 = iou * iou;
                    float m = sc * (i2 * i2 * i2);      // score^1 * iou^6
                    if (m > 0.f) {
                        int c = atomicAdd(&count, 1);
                        if (c < CAP) { cmet[c] = m; cidx[c] = l; }
                    }
                }
            }
            __syncthreads();
            int p = min(count, CAP);

            if (p > TOPKN) {
                for (int t = 0; t < TOPKN; t++) {
                    float bv = -1.f; int bl = 1 << 30, bc = 0;
                    for (int c = tid; c < p; c += NTHR) {
                        float v = cmet[c];
                        int l = cidx[c];
                        if (v > bv || (v == bv && l < bl)) { bv = v; bl = l; bc = c; }
                    }
                    #pragma unroll
                    for (int off = 32; off > 0; off >>= 1) {
                        float ov = __shfl_down(bv, off);
                        int ol = __shfl_down(bl, off);
                        int oc = __shfl_down(bc, off);
                        if (ov > bv || (ov == bv && ol < bl)) { bv = ov; bl = ol; bc = oc; }
                    }
                    int w = tid >> 6;
                    if ((tid & 63) == 0) { rv[w] = bv; rl[w] = bl; rc[w] = bc; }
                    __syncthreads();
                    if (tid == 0) {
                        float fv = rv[0]; int fl = rl[0], fc = rc[0];
                        #pragma unroll
                        for (int w2 = 1; w2 < 4; w2++) {
                            if (rv[w2] > fv || (rv[w2] == fv && rl[w2] < fl)) {
                                fv = rv[w2]; fl = rl[w2]; fc = rc[w2];
                            }
                        }
                        sel[t] = fl;
                        cmet[fc] = -1.f;
                    }
                    __syncthreads();
                }
                if (tid < TOPKN) atomicOr(&posmask[(size_t)b * Ln + sel[tid]], 1u << i);
            } else {
                // all positives selected (p <= 13)
                if (tid < p) atomicOr(&posmask[(size_t)b * Ln + cidx[tid]], 1u << i);
                // remaining slots: lowest-index zero-valued elements across all L;
                // they contribute a bit only if inside the gt box.
                if (tid == 0) {
                    int need = TOPKN - p;
                    for (int l = 0; need > 0 && l < Ln; l++) {
                        bool isc = false;
                        for (int j = 0; j < p; j++) isc |= (cidx[j] == l);
                        if (isc) continue;
                        need--;
                        float2 av = ap[l];
                        float dmin = fminf(fminf(av.x - gx0, av.y - gy0),
                                           fminf(gx1 - av.x, gy1 - av.y));
                        if (dmin > EPSF) atomicOr(&posmask[(size_t)b * Ln + l], 1u << i);
                    }
                }
            }
        }
    }
    gg.sync();

    // ---------------- phase 2: resolve multi-assignment ----------------
    for (int bl = gtid; bl < Bn * Ln; bl += GSZ) {
        int b = bl / Ln;
        u32 pm = posmask[bl];
        u32 fm = pm;
        float4 pbox = ((const float4*)pred_bboxes)[bl];
        const float4* gb = (const float4*)(gt_bboxes + (size_t)b * Ngt * 4);
        if (__popc(pm) > 1) {
            // replace column with one-hot of argmax_i iou (lowest i on ties)
            float best = -1.f; int bi2 = 0;
            for (int i = 0; i < Ngt; i++) {
                float4 g = gb[i];
                float v = iou_box(g.x, g.y, g.z, g.w, pbox);
                if (v > best) { best = v; bi2 = i; }
            }
            fm = 1u << bi2;
        }
        finalmask[bl] = fm;
        int idx = fm ? (__ffs((int)fm) - 1) : 0;
        int src = b * Ngt + idx;
        srcidx[bl] = src;
        float met = 0.f;
        if (fm) {
            float4 g = gb[idx];
            float iou = iou_box(g.x, g.y, g.z, g.w, pbox);
            float sc = pred_scores[(size_t)bl * Cn + gt_labels[src]];
            float i2 = iou * iou;
            met = sc * (i2 * i2 * i2);
            atomicMax((int*)&maxm[src],   __float_as_int(met));  // values >= 0
            atomicMax((int*)&maxiou[src], __float_as_int(iou));
        }
        met_sel[bl] = met;
    }
    gg.sync();

    // ---------------- phase 3: gathers + epilogue ----------------
    {
        const int QPER = (Kpt * 3) / 4;                 // 51 float4 per (b,l)
        const int total = Bn * Ln * QPER;               // 6,854,400 per array
        const int nq = 2 * total;
        const int ntot = nq + Bn * Ln;
        for (int t = gtid; t < ntot; t += GSZ) {
            if (t < nq) {
                const float* ga = gt_poses;
                float4* outp = (float4*)(out + OFF_POSES);
                int qq = t;
                if (qq >= total) { qq -= total; ga = gt_verts; outp = (float4*)(out + OFF_VERTS); }
                int bl = qq / QPER;
                int r = qq - bl * QPER;
                int src = srcidx[bl];
                outp[qq] = ((const float4*)ga)[src * QPER + r];
                continue;
            }
            int bl = t - nq;
            const int bg = *bg_index_p;
            u32 fm = finalmask[bl];
            int src = srcidx[bl];
            int label = fm ? gt_labels[src] : bg;
            float am = 0.f;
            if (fm) am = met_sel[bl] / (maxm[src] + EPSF) * maxiou[src];
            // keep = columns of one_hot(C+1) excluding bg; C=1 -> single kept column
            int keep0 = (bg == 0) ? 1 : 0;
            float sc = (label == keep0) ? am : 0.f;

            out[OFF_LABELS + bl] = (float)label;
            out[OFF_SCORES + bl] = sc;
            out[OFF_GTIDX  + bl] = (float)src;
            ((float4*)(out + OFF_BBOXES))[bl] = ((const float4*)gt_bboxes)[src];
            const float* rs = gt_rot + src * 9;
            float* rd = out + OFF_ROT + (size_t)bl * 9;
#pragma unroll
            for (int j = 0; j < 9; j++) rd[j] = rs[j];
        }
    }
}

extern "C" void kernel_launch(void* const* d_in, const int* in_sizes, int n_in,
                              void* d_out, int out_size, void* d_ws, size_t ws_size,
                              hipStream_t stream)
{
    const float* pred_scores = (const float*)d_in[0];
    const float* pred_bboxes = (const float*)d_in[1];
    const float* anchors     = (const float*)d_in[2];
    const int*   gt_labels   = (const int*)d_in[3];
    const float* gt_bboxes   = (const float*)d_in[4];
    const float* gt_poses    = (const float*)d_in[5];
    const float* gt_verts    = (const float*)d_in[6];
    const float* gt_rot      = (const float*)d_in[7];
    const float* pad_mask    = (const float*)d_in[8];
    const int*   bg_index    = (const int*)d_in[9];

    const int nBL = Bn * Ln;
    u32*   posmask  = (u32*)d_ws;
    float* maxm     = (float*)(posmask + nBL);
    float* maxiou   = maxm + Bn * Ngt;
    u32*   finalmask= (u32*)(maxiou + Bn * Ngt);
    int*   srcidx   = (int*)(finalmask + nBL);
    float* met_sel  = (float*)(srcidx + nBL);
    float* outf     = (float*)d_out;

    void* args[] = {
        (void*)&pred_scores, (void*)&pred_bboxes, (void*)&anchors, (void*)&gt_labels,
        (void*)&gt_bboxes, (void*)&gt_poses, (void*)&gt_verts, (void*)&gt_rot,
        (void*)&pad_mask, (void*)&bg_index,
        (void*)&posmask, (void*)&maxm, (void*)&maxiou,
        (void*)&finalmask, (void*)&srcidx, (void*)&met_sel, (void*)&outf
    };
    hipLaunchCooperativeKernel((const void*)fused, dim3(NBLK), dim3(NTHR),
                               args, 0, stream);
}

// Round 4
// 308.466 us; speedup vs baseline: 1.5334x; 1.5334x over previous
//
#include <hip/hip_runtime.h>

#define Bn 16
#define Ln 8400
#define Cn 1
#define Ngt 32
#define Kpt 68
#define TOPKN 13
#define EPSF 1e-9f
#define CAP 2048   // candidate capacity per (b,i); expected max ~350 for this data

typedef unsigned int u32;
typedef float f4v __attribute__((ext_vector_type(4)));  // clang vector: valid for nontemporal builtins

// Output element offsets (float32 elements, flat concat in return order)
#define OFF_LABELS   0
#define OFF_BBOXES   134400
#define OFF_SCORES   672000
#define OFF_POSES    806400
#define OFF_VERTS    28224000
#define OFF_ROT      55641600
#define OFF_GTIDX    56851200

__device__ __forceinline__ float iou_box(float gx0, float gy0, float gx1, float gy1,
                                         float4 p) {
    float ix0 = fmaxf(gx0, p.x), iy0 = fmaxf(gy0, p.y);
    float ix1 = fminf(gx1, p.z), iy1 = fminf(gy1, p.w);
    float ov = fmaxf(ix1 - ix0, 0.f) * fmaxf(iy1 - iy0, 0.f);
    float a1 = fmaxf(gx1 - gx0, 0.f) * fmaxf(gy1 - gy0, 0.f);
    float a2 = fmaxf(p.z - p.x, 0.f) * fmaxf(p.w - p.y, 0.f);
    return ov / (a1 + a2 - ov + EPSF);
}

// K1: one block per (b,i). Compact positive inside-candidates to LDS, then
// 13 argmax rounds over the small list (value desc, index asc tie-break).
// If <13 positive candidates, zero-valued elements are selected by lowest
// index (exactly matching stable top_k over the masked metric array).
__global__ void __launch_bounds__(256) k1_topk(
    const float* __restrict__ pred_scores, const float* __restrict__ pred_bboxes,
    const float* __restrict__ anchors, const int* __restrict__ gt_labels,
    const float* __restrict__ gt_bboxes, const float* __restrict__ pad_mask,
    u32* __restrict__ posmask)
{
    __shared__ float cmet[CAP];
    __shared__ int   cidx[CAP];
    __shared__ int   count;
    __shared__ float rv[4];
    __shared__ int   rl[4], rc[4];
    __shared__ int   sel[TOPKN];

    const int bi = blockIdx.x;          // b*Ngt + i
    const int b = bi >> 5, i = bi & 31;
    const int tid = threadIdx.x;

    if (pad_mask[bi] == 0.f) return;    // uniform: topk_mask zeroes everything

    const float gx0 = gt_bboxes[bi*4+0];
    const float gy0 = gt_bboxes[bi*4+1];
    const float gx1 = gt_bboxes[bi*4+2];
    const float gy1 = gt_bboxes[bi*4+3];
    const int   label = gt_labels[bi];

    const float4* pb = (const float4*)(pred_bboxes + (size_t)b * Ln * 4);
    const float*  ps = pred_scores + (size_t)b * Ln * Cn;
    const float2* ap = (const float2*)anchors;

    if (tid == 0) count = 0;
    __syncthreads();

    for (int l = tid; l < Ln; l += 256) {
        float2 av = ap[l];
        float dmin = fminf(fminf(av.x - gx0, av.y - gy0),
                           fminf(gx1 - av.x, gy1 - av.y));
        if (dmin > EPSF) {
            float4 pv = pb[l];
            float iou = iou_box(gx0, gy0, gx1, gy1, pv);
            float sc = ps[l * Cn + label];
            float i2 = iou * iou;
            float m = sc * (i2 * i2 * i2);      // score^1 * iou^6
            if (m > 0.f) {
                int c = atomicAdd(&count, 1);
                if (c < CAP) { cmet[c] = m; cidx[c] = l; }
            }
        }
    }
    __syncthreads();
    int p = min(count, CAP);

    if (p > TOPKN) {
        for (int t = 0; t < TOPKN; t++) {
            float bv = -1.f; int bl = 1 << 30, bc = 0;
            for (int c = tid; c < p; c += 256) {
                float v = cmet[c];
                int l = cidx[c];
                if (v > bv || (v == bv && l < bl)) { bv = v; bl = l; bc = c; }
            }
            #pragma unroll
            for (int off = 32; off > 0; off >>= 1) {
                float ov = __shfl_down(bv, off);
                int ol = __shfl_down(bl, off);
                int oc = __shfl_down(bc, off);
                if (ov > bv || (ov == bv && ol < bl)) { bv = ov; bl = ol; bc = oc; }
            }
            int w = tid >> 6;
            if ((tid & 63) == 0) { rv[w] = bv; rl[w] = bl; rc[w] = bc; }
            __syncthreads();
            if (tid == 0) {
                float fv = rv[0]; int fl = rl[0], fc = rc[0];
                #pragma unroll
                for (int w2 = 1; w2 < 4; w2++) {
                    if (rv[w2] > fv || (rv[w2] == fv && rl[w2] < fl)) {
                        fv = rv[w2]; fl = rl[w2]; fc = rc[w2];
                    }
                }
                sel[t] = fl;
                cmet[fc] = -1.f;
            }
            __syncthreads();
        }
        if (tid < TOPKN) atomicOr(&posmask[(size_t)b * Ln + sel[tid]], 1u << i);
    } else {
        // all positives selected (all inside -> all count)
        if (tid < p) atomicOr(&posmask[(size_t)b * Ln + cidx[tid]], 1u << i);
        // remaining slots: lowest-index zero-valued elements across all L;
        // they contribute a bit only if inside the gt box.
        if (tid == 0) {
            int need = TOPKN - p;
            for (int l = 0; need > 0 && l < Ln; l++) {
                bool isc = false;
                for (int j = 0; j < p; j++) isc |= (cidx[j] == l);
                if (isc) continue;
                need--;
                float2 av = ap[l];
                float dmin = fminf(fminf(av.x - gx0, av.y - gy0),
                                   fminf(gx1 - av.x, gy1 - av.y));
                if (dmin > EPSF) atomicOr(&posmask[(size_t)b * Ln + l], 1u << i);
            }
        }
    }
}

// K2: per (b,l): resolve multi-assignment (argmax iou over gts), store finalmask
// (<=1 bit), flat src idx, metric at (src,l); atomicMax per-instance metric/iou maxes.
__global__ void __launch_bounds__(256) k2_resolve(
    const float* __restrict__ pred_scores, const float* __restrict__ pred_bboxes,
    const int* __restrict__ gt_labels, const float* __restrict__ gt_bboxes,
    const u32* __restrict__ posmask, u32* __restrict__ finalmask,
    int* __restrict__ srcidx, float* __restrict__ met_sel,
    float* __restrict__ maxm, float* __restrict__ maxiou)
{
    int bl = blockIdx.x * 256 + threadIdx.x;
    if (bl >= Bn * Ln) return;
    int b = bl / Ln;
    u32 pm = posmask[bl];
    u32 fm = pm;
    float4 pbox = ((const float4*)pred_bboxes)[bl];
    const float4* gb = (const float4*)(gt_bboxes + (size_t)b * Ngt * 4);
    if (__popc(pm) > 1) {
        // replace column with one-hot of argmax_i iou (lowest i on ties)
        float best = -1.f; int bi2 = 0;
        for (int i = 0; i < Ngt; i++) {
            float4 g = gb[i];
            float v = iou_box(g.x, g.y, g.z, g.w, pbox);
            if (v > best) { best = v; bi2 = i; }
        }
        fm = 1u << bi2;
    }
    finalmask[bl] = fm;
    int idx = fm ? (__ffs((int)fm) - 1) : 0;
    int src = b * Ngt + idx;
    srcidx[bl] = src;
    float met = 0.f;
    if (fm) {
        float4 g = gb[idx];
        float iou = iou_box(g.x, g.y, g.z, g.w, pbox);
        float sc = pred_scores[(size_t)bl * Cn + gt_labels[src]];
        float i2 = iou * iou;
        met = sc * (i2 * i2 * i2);
        atomicMax((int*)&maxm[src],   __float_as_int(met));  // values >= 0
        atomicMax((int*)&maxiou[src], __float_as_int(iou));
    }
    met_sel[bl] = met;
}

// K3: fused big gathers + epilogue, restructured for pure coalesced streaming:
//   range A: poses+vertices, one float4 per lane (consecutive lanes -> consecutive 16B)
//   range B: rotations, one float per lane (was 9 scalar stride-36 stores per thread)
//   range C: per-(b,l) epilogue (labels/scores/gt_index/bbox)
// All output stores are non-temporal: 228 MB write-once stream must not evict the
// L2-resident gt tables / srcidx that the gathers re-read.
__global__ void __launch_bounds__(256) k3_out(
    const float* __restrict__ gt_poses, const float* __restrict__ gt_verts,
    const u32* __restrict__ finalmask, const int* __restrict__ srcidx,
    const float* __restrict__ met_sel, const float* __restrict__ maxm_a,
    const float* __restrict__ maxiou_a, const int* __restrict__ gt_labels,
    const float* __restrict__ gt_bboxes, const float* __restrict__ gt_rot,
    const int* __restrict__ bg_index_p, float* __restrict__ out)
{
    const int QPER = (Kpt * 3) / 4;                 // 51 float4 per (b,l)
    const int total = Bn * Ln * QPER;               // 6,854,400 per array
    const int nq = 2 * total;
    const int nrot = Bn * Ln * 9;                   // 1,209,600 scalar floats
    int t = blockIdx.x * 256 + threadIdx.x;
    if (t < nq) {
        const float* ga = gt_poses;
        f4v* outp = (f4v*)(out + OFF_POSES);
        int qq = t;
        if (qq >= total) { qq -= total; ga = gt_verts; outp = (f4v*)(out + OFF_VERTS); }
        int bl = qq / QPER;
        int r = qq - bl * QPER;
        int src = srcidx[bl];
        f4v v = ((const f4v*)ga)[src * QPER + r];
        __builtin_nontemporal_store(v, &outp[qq]);
        return;
    }
    t -= nq;
    if (t < nrot) {
        int bl = t / 9;
        int j = t - bl * 9;
        int src = srcidx[bl];
        __builtin_nontemporal_store(gt_rot[src * 9 + j], &out[OFF_ROT + t]);
        return;
    }
    int bl = t - nrot;
    if (bl >= Bn * Ln) return;
    const int bg = *bg_index_p;
    u32 fm = finalmask[bl];
    int src = srcidx[bl];
    int label = fm ? gt_labels[src] : bg;
    float am = 0.f;
    if (fm) am = met_sel[bl] / (maxm_a[src] + EPSF) * maxiou_a[src];
    // keep = columns of one_hot(C+1) excluding bg; C=1 -> single kept column
    int keep0 = (bg == 0) ? 1 : 0;
    float sc = (label == keep0) ? am : 0.f;

    __builtin_nontemporal_store((float)label, &out[OFF_LABELS + bl]);
    __builtin_nontemporal_store(sc,           &out[OFF_SCORES + bl]);
    __builtin_nontemporal_store((float)src,   &out[OFF_GTIDX  + bl]);
    f4v bb = ((const f4v*)gt_bboxes)[src];
    __builtin_nontemporal_store(bb, &((f4v*)(out + OFF_BBOXES))[bl]);
}

extern "C" void kernel_launch(void* const* d_in, const int* in_sizes, int n_in,
                              void* d_out, int out_size, void* d_ws, size_t ws_size,
                              hipStream_t stream)
{
    const float* pred_scores = (const float*)d_in[0];
    const float* pred_bboxes = (const float*)d_in[1];
    const float* anchors     = (const float*)d_in[2];
    const int*   gt_labels   = (const int*)d_in[3];
    const float* gt_bboxes   = (const float*)d_in[4];
    const float* gt_poses    = (const float*)d_in[5];
    const float* gt_verts    = (const float*)d_in[6];
    const float* gt_rot      = (const float*)d_in[7];
    const float* pad_mask    = (const float*)d_in[8];
    const int*   bg_index    = (const int*)d_in[9];

    const int nBL = Bn * Ln;
    u32*   posmask  = (u32*)d_ws;
    float* maxm     = (float*)(posmask + nBL);
    float* maxiou   = maxm + Bn * Ngt;
    u32*   finalmask= (u32*)(maxiou + Bn * Ngt);
    int*   srcidx   = (int*)(finalmask + nBL);
    float* met_sel  = (float*)(srcidx + nBL);

    // zero posmask + maxm + maxiou (contiguous region)
    (void)hipMemsetAsync(posmask, 0, ((size_t)nBL + 2 * Bn * Ngt) * sizeof(u32), stream);

    k1_topk<<<Bn * Ngt, 256, 0, stream>>>(pred_scores, pred_bboxes, anchors,
                                          gt_labels, gt_bboxes, pad_mask, posmask);
    k2_resolve<<<(nBL + 255) / 256, 256, 0, stream>>>(pred_scores, pred_bboxes,
                                                      gt_labels, gt_bboxes, posmask,
                                                      finalmask, srcidx, met_sel,
                                                      maxm, maxiou);
    const int nq = 2 * Bn * Ln * ((Kpt * 3) / 4);
    const int nrot = Bn * Ln * 9;
    const int ntot = nq + nrot + nBL;
    k3_out<<<(ntot + 255) / 256, 256, 0, stream>>>(gt_poses, gt_verts, finalmask,
                                                   srcidx, met_sel, maxm, maxiou,
                                                   gt_labels, gt_bboxes, gt_rot,
                                                   bg_index, (float*)d_out);
}

// Round 5
// 299.791 us; speedup vs baseline: 1.5778x; 1.0289x over previous
//
#include <hip/hip_runtime.h>

#define Bn 16
#define Ln 8400
#define Cn 1
#define Ngt 32
#define Kpt 68
#define TOPKN 13
#define EPSF 1e-9f
#define CAP 2048   // candidate capacity per (b,i); typical p is ~2-80 for this data

typedef unsigned int u32;
typedef float f4v __attribute__((ext_vector_type(4)));  // clang vector: valid for nontemporal builtins

// Output element offsets (float32 elements, flat concat in return order)
#define OFF_LABELS   0
#define OFF_BBOXES   134400
#define OFF_SCORES   672000
#define OFF_POSES    806400
#define OFF_VERTS    28224000
#define OFF_ROT      55641600
#define OFF_GTIDX    56851200

__device__ __forceinline__ float iou_box(float gx0, float gy0, float gx1, float gy1,
                                         float4 p) {
    float ix0 = fmaxf(gx0, p.x), iy0 = fmaxf(gy0, p.y);
    float ix1 = fminf(gx1, p.z), iy1 = fminf(gy1, p.w);
    float ov = fmaxf(ix1 - ix0, 0.f) * fmaxf(iy1 - iy0, 0.f);
    float a1 = fmaxf(gx1 - gx0, 0.f) * fmaxf(gy1 - gy0, 0.f);
    float a2 = fmaxf(p.z - p.x, 0.f) * fmaxf(p.w - p.y, 0.f);
    return ov / (a1 + a2 - ov + EPSF);
}

// K1: one block per (b,i). Emits selg[bi][0..12] = the 13 top-k anchor indices
// (value desc, index asc tie-break over metric*inside; slots that correspond to
// zero-valued picks that fail the inside test are -1, i.e. contribute no bit).
// No zeroed posmask needed -> no memset dispatch. Also zeroes maxm/maxiou.
__global__ void __launch_bounds__(256) k1_topk(
    const float* __restrict__ pred_scores, const float* __restrict__ pred_bboxes,
    const float* __restrict__ anchors, const int* __restrict__ gt_labels,
    const float* __restrict__ gt_bboxes, const float* __restrict__ pad_mask,
    int* __restrict__ selg, float* __restrict__ maxm /* maxm|maxiou contiguous */)
{
    __shared__ float cmet[CAP];
    __shared__ int   cidx[CAP];
    __shared__ int   count;
    __shared__ float rv[4];
    __shared__ int   rl[4], rc[4];
    __shared__ int   sel[TOPKN];

    const int bi = blockIdx.x;          // b*Ngt + i
    const int b = bi >> 5;
    const int tid = threadIdx.x;

    // zero per-instance accumulators (2*Bn*Ngt = 1024 floats) before k2 runs
    { int z = bi * 256 + tid; if (z < 2 * Bn * Ngt) maxm[z] = 0.f; }

    if (pad_mask[bi] == 0.f) {          // uniform: topk_mask zeroes everything
        if (tid < TOPKN) selg[bi * TOPKN + tid] = -1;
        return;
    }

    const float gx0 = gt_bboxes[bi*4+0];
    const float gy0 = gt_bboxes[bi*4+1];
    const float gx1 = gt_bboxes[bi*4+2];
    const float gy1 = gt_bboxes[bi*4+3];
    const int   label = gt_labels[bi];

    const float4* pb = (const float4*)(pred_bboxes + (size_t)b * Ln * 4);
    const float*  ps = pred_scores + (size_t)b * Ln * Cn;
    const float2* ap = (const float2*)anchors;

    if (tid == 0) count = 0;
    __syncthreads();

    for (int l = tid; l < Ln; l += 256) {
        float2 av = ap[l];
        float dmin = fminf(fminf(av.x - gx0, av.y - gy0),
                           fminf(gx1 - av.x, gy1 - av.y));
        if (dmin > EPSF) {
            float4 pv = pb[l];
            float iou = iou_box(gx0, gy0, gx1, gy1, pv);
            float sc = ps[l * Cn + label];
            float i2 = iou * iou;
            float m = sc * (i2 * i2 * i2);      // score^1 * iou^6
            if (m > 0.f) {
                int c = atomicAdd(&count, 1);
                if (c < CAP) { cmet[c] = m; cidx[c] = l; }
            }
        }
    }
    __syncthreads();
    int p = min(count, CAP);

    if (p > TOPKN) {
        for (int t = 0; t < TOPKN; t++) {
            float bv = -1.f; int bl = 1 << 30, bc = 0;
            for (int c = tid; c < p; c += 256) {
                float v = cmet[c];
                int l = cidx[c];
                if (v > bv || (v == bv && l < bl)) { bv = v; bl = l; bc = c; }
            }
            #pragma unroll
            for (int off = 32; off > 0; off >>= 1) {
                float ov = __shfl_down(bv, off);
                int ol = __shfl_down(bl, off);
                int oc = __shfl_down(bc, off);
                if (ov > bv || (ov == bv && ol < bl)) { bv = ov; bl = ol; bc = oc; }
            }
            int w = tid >> 6;
            if ((tid & 63) == 0) { rv[w] = bv; rl[w] = bl; rc[w] = bc; }
            __syncthreads();
            if (tid == 0) {
                float fv = rv[0]; int fl = rl[0], fc = rc[0];
                #pragma unroll
                for (int w2 = 1; w2 < 4; w2++) {
                    if (rv[w2] > fv || (rv[w2] == fv && rl[w2] < fl)) {
                        fv = rv[w2]; fl = rl[w2]; fc = rc[w2];
                    }
                }
                sel[t] = fl;
                cmet[fc] = -1.f;
            }
            __syncthreads();
        }
        if (tid < TOPKN) selg[bi * TOPKN + tid] = sel[tid];
    } else {
        // all positives selected
        if (tid < p) selg[bi * TOPKN + tid] = cidx[tid];
        // remaining slots: lowest-index zero-valued elements across all L
        // (stable top_k tie-break); they contribute only if inside the gt box.
        if (tid == 0) {
            int pos = p;
            for (int l = 0; pos < TOPKN && l < Ln; l++) {
                bool isc = false;
                for (int j = 0; j < p; j++) isc |= (cidx[j] == l);
                if (isc) continue;
                float2 av = ap[l];
                float dmin = fminf(fminf(av.x - gx0, av.y - gy0),
                                   fminf(gx1 - av.x, gy1 - av.y));
                selg[bi * TOPKN + pos] = (dmin > EPSF) ? l : -1;
                pos++;
            }
        }
    }
}

// K2: grid (33, Bn); each block serves one batch, stages the 416-entry sel list
// into LDS, rebuilds the per-anchor gt bitmask, then resolves multi-assignment
// (argmax iou over gts), stores finalmask/srcidx/met_sel; atomicMax per-instance
// metric/iou maxes.
__global__ void __launch_bounds__(256) k2_resolve(
    const float* __restrict__ pred_scores, const float* __restrict__ pred_bboxes,
    const int* __restrict__ gt_labels, const float* __restrict__ gt_bboxes,
    const int* __restrict__ selg, u32* __restrict__ finalmask,
    int* __restrict__ srcidx, float* __restrict__ met_sel,
    float* __restrict__ maxm, float* __restrict__ maxiou)
{
    __shared__ int ssel[Ngt * TOPKN];
    const int b = blockIdx.y;
    const int l = blockIdx.x * 256 + threadIdx.x;
    for (int z = threadIdx.x; z < Ngt * TOPKN; z += 256)
        ssel[z] = selg[b * Ngt * TOPKN + z];
    __syncthreads();
    if (l >= Ln) return;
    const int bl = b * Ln + l;

    u32 pm = 0;
    #pragma unroll 4
    for (int i = 0; i < Ngt; i++) {
        u32 hit = 0;
        #pragma unroll
        for (int j = 0; j < TOPKN; j++) hit |= (u32)(ssel[i * TOPKN + j] == l);
        pm |= hit << i;
    }

    u32 fm = pm;
    float4 pbox = ((const float4*)pred_bboxes)[bl];
    const float4* gb = (const float4*)(gt_bboxes + (size_t)b * Ngt * 4);
    if (__popc(pm) > 1) {
        // replace column with one-hot of argmax_i iou (lowest i on ties)
        float best = -1.f; int bi2 = 0;
        for (int i = 0; i < Ngt; i++) {
            float4 g = gb[i];
            float v = iou_box(g.x, g.y, g.z, g.w, pbox);
            if (v > best) { best = v; bi2 = i; }
        }
        fm = 1u << bi2;
    }
    finalmask[bl] = fm;
    int idx = fm ? (__ffs((int)fm) - 1) : 0;
    int src = b * Ngt + idx;
    srcidx[bl] = src;
    float met = 0.f;
    if (fm) {
        float4 g = gb[idx];
        float iou = iou_box(g.x, g.y, g.z, g.w, pbox);
        float sc = pred_scores[(size_t)bl * Cn + gt_labels[src]];
        float i2 = iou * iou;
        met = sc * (i2 * i2 * i2);
        atomicMax((int*)&maxm[src],   __float_as_int(met));  // values >= 0
        atomicMax((int*)&maxiou[src], __float_as_int(iou));
    }
    met_sel[bl] = met;
}

// K3: fused big gathers + epilogue, pure coalesced streaming:
//   range A: poses+vertices PAIRED per thread (same src, same r -> shared
//            srcidx load + address math; 2x16B nt stores, both coalesced)
//   range B: rotations, one float per lane
//   range C: per-(b,l) epilogue (labels/scores/gt_index/bbox)
// Non-temporal stores: 228 MB write-once stream must not evict the
// L2-resident gt tables / srcidx that the gathers re-read.
__global__ void __launch_bounds__(256) k3_out(
    const float* __restrict__ gt_poses, const float* __restrict__ gt_verts,
    const u32* __restrict__ finalmask, const int* __restrict__ srcidx,
    const float* __restrict__ met_sel, const float* __restrict__ maxm_a,
    const float* __restrict__ maxiou_a, const int* __restrict__ gt_labels,
    const float* __restrict__ gt_bboxes, const float* __restrict__ gt_rot,
    const int* __restrict__ bg_index_p, float* __restrict__ out)
{
    const int QPER = (Kpt * 3) / 4;                 // 51 float4 per (b,l)
    const int totalA = Bn * Ln * QPER;              // 6,854,400 paired float4s
    const int nrot = Bn * Ln * 9;                   // 1,209,600 scalar floats
    int t = blockIdx.x * 256 + threadIdx.x;
    if (t < totalA) {
        int bl = t / QPER;
        int r = t - bl * QPER;
        int src = srcidx[bl];
        f4v pv = ((const f4v*)gt_poses)[src * QPER + r];
        f4v vv = ((const f4v*)gt_verts)[src * QPER + r];
        __builtin_nontemporal_store(pv, &((f4v*)(out + OFF_POSES))[t]);
        __builtin_nontemporal_store(vv, &((f4v*)(out + OFF_VERTS))[t]);
        return;
    }
    t -= totalA;
    if (t < nrot) {
        int bl = t / 9;
        int j = t - bl * 9;
        int src = srcidx[bl];
        __builtin_nontemporal_store(gt_rot[src * 9 + j], &out[OFF_ROT + t]);
        return;
    }
    int bl = t - nrot;
    if (bl >= Bn * Ln) return;
    const int bg = *bg_index_p;
    u32 fm = finalmask[bl];
    int src = srcidx[bl];
    int label = fm ? gt_labels[src] : bg;
    float am = 0.f;
    if (fm) am = met_sel[bl] / (maxm_a[src] + EPSF) * maxiou_a[src];
    // keep = columns of one_hot(C+1) excluding bg; C=1 -> single kept column
    int keep0 = (bg == 0) ? 1 : 0;
    float sc = (label == keep0) ? am : 0.f;

    __builtin_nontemporal_store((float)label, &out[OFF_LABELS + bl]);
    __builtin_nontemporal_store(sc,           &out[OFF_SCORES + bl]);
    __builtin_nontemporal_store((float)src,   &out[OFF_GTIDX  + bl]);
    f4v bb = ((const f4v*)gt_bboxes)[src];
    __builtin_nontemporal_store(bb, &((f4v*)(out + OFF_BBOXES))[bl]);
}

extern "C" void kernel_launch(void* const* d_in, const int* in_sizes, int n_in,
                              void* d_out, int out_size, void* d_ws, size_t ws_size,
                              hipStream_t stream)
{
    const float* pred_scores = (const float*)d_in[0];
    const float* pred_bboxes = (const float*)d_in[1];
    const float* anchors     = (const float*)d_in[2];
    const int*   gt_labels   = (const int*)d_in[3];
    const float* gt_bboxes   = (const float*)d_in[4];
    const float* gt_poses    = (const float*)d_in[5];
    const float* gt_verts    = (const float*)d_in[6];
    const float* gt_rot      = (const float*)d_in[7];
    const float* pad_mask    = (const float*)d_in[8];
    const int*   bg_index    = (const int*)d_in[9];

    const int nBL = Bn * Ln;
    int*   selg     = (int*)d_ws;                       // Bn*Ngt*TOPKN
    float* maxm     = (float*)(selg + Bn * Ngt * TOPKN);// Bn*Ngt
    float* maxiou   = maxm + Bn * Ngt;                  // Bn*Ngt (contiguous w/ maxm)
    u32*   finalmask= (u32*)(maxiou + Bn * Ngt);
    int*   srcidx   = (int*)(finalmask + nBL);
    float* met_sel  = (float*)(srcidx + nBL);

    // no memset dispatch: selg fully written by k1; maxm/maxiou zeroed in k1;
    // finalmask/srcidx/met_sel fully written by k2.

    k1_topk<<<Bn * Ngt, 256, 0, stream>>>(pred_scores, pred_bboxes, anchors,
                                          gt_labels, gt_bboxes, pad_mask,
                                          selg, maxm);
    k2_resolve<<<dim3((Ln + 255) / 256, Bn), 256, 0, stream>>>(
        pred_scores, pred_bboxes, gt_labels, gt_bboxes, selg,
        finalmask, srcidx, met_sel, maxm, maxiou);
    const int totalA = Bn * Ln * ((Kpt * 3) / 4);
    const int nrot = Bn * Ln * 9;
    const int ntot = totalA + nrot + nBL;
    k3_out<<<(ntot + 255) / 256, 256, 0, stream>>>(gt_poses, gt_verts, finalmask,
                                                   srcidx, met_sel, maxm, maxiou,
                                                   gt_labels, gt_bboxes, gt_rot,
                                                   bg_index, (float*)d_out);
}